// Round 9
// baseline (3011.900 us; speedup 1.0000x reference)
//
#include <hip/hip_runtime.h>
#include <hip/hip_bf16.h>

#define NN 8192
#define DD 64
#define NITER 100

typedef unsigned short u16;
typedef unsigned int u32;
typedef float nfloat4 __attribute__((ext_vector_type(4)));  // native vec for NT store

static constexpr float INV_EPS = 10.0f;          // 1/epsilon
static constexpr float MARG    = 1.0f / 8192.0f; // a_i = b_j = u0_i = 1/n

// Unpack 8 bf16 (packed in uint4) -> 8 f32 (exact: bf16 is truncated f32)
__device__ __forceinline__ void unpack8(const uint4 q, float f[8]) {
  f[0] = __uint_as_float(q.x << 16); f[1] = __uint_as_float(q.x & 0xffff0000u);
  f[2] = __uint_as_float(q.y << 16); f[3] = __uint_as_float(q.y & 0xffff0000u);
  f[4] = __uint_as_float(q.z << 16); f[5] = __uint_as_float(q.z & 0xffff0000u);
  f[6] = __uint_as_float(q.w << 16); f[7] = __uint_as_float(q.w & 0xffff0000u);
}

// Pack two f32 -> u32 of 2 bf16 (RNE), low half = first element
__device__ __forceinline__ u32 pkbf2(float a, float b) {
  __hip_bfloat16 ha = __float2bfloat16(a), hb = __float2bfloat16(b);
  return (u32)*reinterpret_cast<u16*>(&ha) | ((u32)*reinterpret_cast<u16*>(&hb) << 16);
}

// ---------------------------------------------------------------------------
// Kernel 1: row norms of x and y. 16384 threads, one row each.
__global__ __launch_bounds__(256) void norms_k(const float* __restrict__ x,
                                               const float* __restrict__ y,
                                               float* __restrict__ xx,
                                               float* __restrict__ yy) {
  int idx = blockIdx.x * 256 + threadIdx.x;       // 0..16383
  const float* src = (idx < NN) ? (x + (size_t)idx * DD)
                                : (y + (size_t)(idx - NN) * DD);
  const float4* p = (const float4*)src;
  float s = 0.f;
#pragma unroll
  for (int i = 0; i < 16; i++) {
    float4 v = p[i];
    s += v.x * v.x + v.y * v.y + v.z * v.z + v.w * v.w;
  }
  if (idx < NN) xx[idx] = s; else yy[idx - NN] = s;
}

// ---------------------------------------------------------------------------
// Kernel 2: build K (bf16), LDS-tiled f32 GEMM. 128x128 tile, micro 8x(4+4):
// per k-step 4 ds_read_b128 feed 64 FMAs (was 3:32) -> VALU is ~all FMA.
// Grid = 64 row-blocks x 64 col-blocks = 4096. LDS 64 KB -> 2 blocks/CU.
// xs reads: 16-lane broadcast (free); ys reads & staging writes 2-way (free).
__global__ __launch_bounds__(256) void build_k(const float* __restrict__ x,
                                               const float* __restrict__ y,
                                               const float* __restrict__ xx,
                                               const float* __restrict__ yy,
                                               u16* __restrict__ K) {
  __shared__ float xs[64][128];   // [k][row]  32 KB
  __shared__ float ys[64][128];   // [k][col]  32 KB

  int t  = threadIdx.x;
  int ib = blockIdx.x & 63;       // row block 0..63
  int jb = blockIdx.x >> 6;       // col block 0..63
  int i0 = ib * 128;
  int j0 = jb * 128;

  // stage x tile (128 rows x 64 k): thread t -> row t&127, k-chunk (t>>7)*32.
  // Transposed writes: bank = row&31, rows distinct per wave -> 2-way (free).
  {
    int row = t & 127, kc = (t >> 7) * 32;
    const float4* src = (const float4*)(x + (size_t)(i0 + row) * DD + kc);
#pragma unroll
    for (int c = 0; c < 8; c++) {
      float4 v = src[c];
      xs[kc + c * 4 + 0][row] = v.x;
      xs[kc + c * 4 + 1][row] = v.y;
      xs[kc + c * 4 + 2][row] = v.z;
      xs[kc + c * 4 + 3][row] = v.w;
    }
  }
  // stage y tile (128 cols x 64 k): same structure.
  {
    int col = t & 127, kc = (t >> 7) * 32;
    const float4* src = (const float4*)(y + (size_t)(j0 + col) * DD + kc);
#pragma unroll
    for (int c = 0; c < 8; c++) {
      float4 v = src[c];
      ys[kc + c * 4 + 0][col] = v.x;
      ys[kc + c * 4 + 1][col] = v.y;
      ys[kc + c * 4 + 2][col] = v.z;
      ys[kc + c * 4 + 3][col] = v.w;
    }
  }
  __syncthreads();

  int tr = (t >> 4) * 8;          // row offset: 0,8,..,120
  int tc = (t & 15) * 4;          // col group 1; group 2 at tc+64

  float acc[8][8];
#pragma unroll
  for (int r = 0; r < 8; r++)
#pragma unroll
    for (int c = 0; c < 8; c++) acc[r][c] = 0.f;

#pragma unroll 2
  for (int k = 0; k < DD; k++) {
    float4 xa0 = *(const float4*)&xs[k][tr];       // 16-lane broadcast: free
    float4 xa1 = *(const float4*)&xs[k][tr + 4];
    float4 y0  = *(const float4*)&ys[k][tc];       // 2-way: free
    float4 y1  = *(const float4*)&ys[k][tc + 64];  // 2-way: free
    float xv[8] = {xa0.x, xa0.y, xa0.z, xa0.w, xa1.x, xa1.y, xa1.z, xa1.w};
    float yv[8] = {y0.x, y0.y, y0.z, y0.w, y1.x, y1.y, y1.z, y1.w};
#pragma unroll
    for (int r = 0; r < 8; r++)
#pragma unroll
      for (int c = 0; c < 8; c++) acc[r][c] += xv[r] * yv[c];
  }

  float xn[8], yn[8];
#pragma unroll
  for (int r = 0; r < 8; r++) xn[r] = xx[i0 + tr + r];
#pragma unroll
  for (int c = 0; c < 4; c++) {
    yn[c]     = yy[j0 + tc + c];
    yn[c + 4] = yy[j0 + 64 + tc + c];
  }

#pragma unroll
  for (int r = 0; r < 8; r++) {
    u32 o[4];
#pragma unroll
    for (int c = 0; c < 8; c += 2) {
      float sqa = fmaxf(xn[r] + yn[c]     - 2.f * acc[r][c],     1e-12f);
      float sqb = fmaxf(xn[r] + yn[c + 1] - 2.f * acc[r][c + 1], 1e-12f);
      float ka = __expf(-sqrtf(sqa) * INV_EPS);
      float kb = __expf(-sqrtf(sqb) * INV_EPS);
      o[c >> 1] = pkbf2(ka, kb);
    }
    u16* base = K + (size_t)(i0 + tr + r) * NN + j0;
    *(uint2*)(base + tc)      = make_uint2(o[0], o[1]);
    *(uint2*)(base + 64 + tc) = make_uint2(o[2], o[3]);
  }
}

// ---------------------------------------------------------------------------
// Kernel 3: initial column partials (u0 = 1/n), P bf16.
__global__ __launch_bounds__(256) void col0_k(const u16* __restrict__ K,
                                              u16* __restrict__ P) {
  int t = threadIdx.x;
  int b = blockIdx.x;
  int i0 = b * 16;
  float acc[4][8];
#pragma unroll
  for (int c = 0; c < 4; c++)
#pragma unroll
    for (int e = 0; e < 8; e++) acc[c][e] = 0.f;

  for (int r = 0; r < 16; r++) {
#pragma unroll
    for (int c = 0; c < 4; c++) {
      uint4 q = *(const uint4*)(K + (size_t)(i0 + r) * NN + c * 2048 + t * 8);
      float f[8];
      unpack8(q, f);
#pragma unroll
      for (int e = 0; e < 8; e++) acc[c][e] += f[e];
    }
  }
#pragma unroll
  for (int c = 0; c < 4; c++) {
    uint4 w;
    w.x = pkbf2(acc[c][0] * MARG, acc[c][1] * MARG);
    w.y = pkbf2(acc[c][2] * MARG, acc[c][3] * MARG);
    w.z = pkbf2(acc[c][4] * MARG, acc[c][5] * MARG);
    w.w = pkbf2(acc[c][6] * MARG, acc[c][7] * MARG);
    *(uint4*)(P + (size_t)b * NN + c * 2048 + t * 8) = w;
  }
}

// ---------------------------------------------------------------------------
// Kernel 4: reduce bf16 partials -> v[j] = b_j / sum_k P[k][j].
// 256 blocks x 32 cols (measured-good shape for this latency-bound reduce).
__global__ __launch_bounds__(256) void red_k(const u16* __restrict__ P,
                                             float* __restrict__ v) {
  int t = threadIdx.x;
  int j0 = blockIdx.x * 32;
  int jjp = t & 15;               // col-pair 0..15
  int kk  = t >> 4;               // 0..15, 32 partial rows each
  float s0 = 0.f, s1 = 0.f;
#pragma unroll 8
  for (int k = kk * 32; k < kk * 32 + 32; k++) {
    u32 w = *(const u32*)(P + (size_t)k * NN + j0 + jjp * 2);
    s0 += __uint_as_float(w << 16);
    s1 += __uint_as_float(w & 0xffff0000u);
  }
  __shared__ float red[256][2];
  red[t][0] = s0;
  red[t][1] = s1;
  __syncthreads();
  if (t < 16) {
    float t0 = 0.f, t1 = 0.f;
#pragma unroll
    for (int k = 0; k < 16; k++) {
      t0 += red[k * 16 + t][0];
      t1 += red[k * 16 + t][1];
    }
    v[j0 + t * 2]     = MARG / t0;
    v[j0 + t * 2 + 1] = MARG / t1;
  }
}

// ---------------------------------------------------------------------------
// Kernel 5 (hot loop): fused row-dot + column-partial. Known-good structure:
// 16 rows per block, 8 groups of 2; one barrier per group; 108 VGPR, no
// spill. At the fabric-BW roofline (~5.9 of 6.3-6.6 TB/s) — do not touch.
__global__ __launch_bounds__(256) void fused_k(const u16* __restrict__ K,
                                               const float* __restrict__ vin,
                                               float* __restrict__ uout,
                                               u16* __restrict__ P) {
  int t = threadIdx.x;
  int b = blockIdx.x;
  int i0 = b * 16;
  int wave = t >> 6;

  // v values for this thread's 32 columns
  float vv[4][8];
#pragma unroll
  for (int c = 0; c < 4; c++) {
    const float* vp = vin + c * 2048 + t * 8;
    float4 a = *(const float4*)vp;
    float4 bq = *(const float4*)(vp + 4);
    vv[c][0] = a.x;  vv[c][1] = a.y;  vv[c][2] = a.z;  vv[c][3] = a.w;
    vv[c][4] = bq.x; vv[c][5] = bq.y; vv[c][6] = bq.z; vv[c][7] = bq.w;
  }

  float acc[4][8];
#pragma unroll
  for (int c = 0; c < 4; c++)
#pragma unroll
    for (int e = 0; e < 8; e++) acc[c][e] = 0.f;

  __shared__ float wsum[2][4][2];   // [buf][wave][row]

  for (int rg = 0; rg < 8; rg++) {
    int i = i0 + rg * 2;
    uint4 q0[4], q1[4];
#pragma unroll
    for (int c = 0; c < 4; c++) {
      q0[c] = *(const uint4*)(K + (size_t)i * NN + c * 2048 + t * 8);
      q1[c] = *(const uint4*)(K + (size_t)(i + 1) * NN + c * 2048 + t * 8);
    }
    float s0 = 0.f, s1 = 0.f;
#pragma unroll
    for (int c = 0; c < 4; c++) {
      float f[8];
      unpack8(q0[c], f);
#pragma unroll
      for (int e = 0; e < 8; e++) s0 += f[e] * vv[c][e];
      unpack8(q1[c], f);
#pragma unroll
      for (int e = 0; e < 8; e++) s1 += f[e] * vv[c][e];
    }
    // wave-level reduce (64 lanes)
#pragma unroll
    for (int o = 32; o > 0; o >>= 1) {
      s0 += __shfl_xor(s0, o);
      s1 += __shfl_xor(s1, o);
    }
    if ((t & 63) == 0) {
      wsum[rg & 1][wave][0] = s0;
      wsum[rg & 1][wave][1] = s1;
    }
    __syncthreads();
    float u0 = MARG / (wsum[rg & 1][0][0] + wsum[rg & 1][1][0]
                     + wsum[rg & 1][2][0] + wsum[rg & 1][3][0]);
    float u1 = MARG / (wsum[rg & 1][0][1] + wsum[rg & 1][1][1]
                     + wsum[rg & 1][2][1] + wsum[rg & 1][3][1]);
    if (t < 2) uout[i + t] = (t == 0) ? u0 : u1;

    // accumulate column partials (re-unpack from regs)
#pragma unroll
    for (int c = 0; c < 4; c++) {
      float f[8];
      unpack8(q0[c], f);
#pragma unroll
      for (int e = 0; e < 8; e++) acc[c][e] += f[e] * u0;
      unpack8(q1[c], f);
#pragma unroll
      for (int e = 0; e < 8; e++) acc[c][e] += f[e] * u1;
    }
  }

#pragma unroll
  for (int c = 0; c < 4; c++) {
    uint4 w;
    w.x = pkbf2(acc[c][0], acc[c][1]);
    w.y = pkbf2(acc[c][2], acc[c][3]);
    w.z = pkbf2(acc[c][4], acc[c][5]);
    w.w = pkbf2(acc[c][6], acc[c][7]);
    *(uint4*)(P + (size_t)b * NN + c * 2048 + t * 8) = w;
  }
}

// ---------------------------------------------------------------------------
// Kernel 6: pi[i][j] = u_i * K[i][j] * v_j. 4096 blocks x 2 rows; NT stores.
__global__ __launch_bounds__(256) void pi_k(const u16* __restrict__ K,
                                            const float* __restrict__ u,
                                            const float* __restrict__ v,
                                            float* __restrict__ out) {
  int t = threadIdx.x;
  int b = blockIdx.x;
  int i0 = b * 2;

  float vv[4][8];
#pragma unroll
  for (int c = 0; c < 4; c++) {
    const float* vp = v + c * 2048 + t * 8;
    float4 a = *(const float4*)vp;
    float4 bq = *(const float4*)(vp + 4);
    vv[c][0] = a.x;  vv[c][1] = a.y;  vv[c][2] = a.z;  vv[c][3] = a.w;
    vv[c][4] = bq.x; vv[c][5] = bq.y; vv[c][6] = bq.z; vv[c][7] = bq.w;
  }

#pragma unroll
  for (int r = 0; r < 2; r++) {
    int i = i0 + r;
    float uv = u[i];
#pragma unroll
    for (int c = 0; c < 4; c++) {
      uint4 q = *(const uint4*)(K + (size_t)i * NN + c * 2048 + t * 8);
      float f[8];
      unpack8(q, f);
      nfloat4 lo = {uv * f[0] * vv[c][0], uv * f[1] * vv[c][1],
                    uv * f[2] * vv[c][2], uv * f[3] * vv[c][3]};
      nfloat4 hi = {uv * f[4] * vv[c][4], uv * f[5] * vv[c][5],
                    uv * f[6] * vv[c][6], uv * f[7] * vv[c][7]};
      float* dst = out + (size_t)i * NN + c * 2048 + t * 8;
      __builtin_nontemporal_store(lo, (nfloat4*)dst);
      __builtin_nontemporal_store(hi, (nfloat4*)(dst + 4));
    }
  }
}

// ---------------------------------------------------------------------------
extern "C" void kernel_launch(void* const* d_in, const int* in_sizes, int n_in,
                              void* d_out, int out_size, void* d_ws, size_t ws_size,
                              hipStream_t stream) {
  const float* x = (const float*)d_in[0];
  const float* y = (const float*)d_in[1];
  float* out = (float*)d_out;

  char* ws = (char*)d_ws;
  u16*  K  = (u16*)ws;                                     // 128 MiB
  u16*  P  = (u16*)(ws + (size_t)NN * NN * 2);             // 8 MiB (512 x 8192 bf16)
  float* xx = (float*)(ws + (size_t)NN * NN * 2 + (size_t)512 * NN * 2);
  float* yy = xx + NN;
  float* u  = yy + NN;
  float* v  = u + NN;

  norms_k<<<(2 * NN) / 256, 256, 0, stream>>>(x, y, xx, yy);
  build_k<<<64 * 64, 256, 0, stream>>>(x, y, xx, yy, K);
  col0_k<<<NN / 16, 256, 0, stream>>>(K, P);               // P = partials of K^T u0

  for (int it = 0; it < NITER; it++) {
    red_k<<<NN / 32, 256, 0, stream>>>(P, v);              // v = b / (K^T u)
    fused_k<<<NN / 16, 256, 0, stream>>>(K, v, u, P);      // u = a/(Kv); P = partials K^T u
  }
  red_k<<<NN / 32, 256, 0, stream>>>(P, v);                // final v
  pi_k<<<NN / 2, 256, 0, stream>>>(K, u, v, out);          // pi = u * K * v
}

// Round 10
// 3007.820 us; speedup vs baseline: 1.0014x; 1.0014x over previous
//
#include <hip/hip_runtime.h>
#include <hip/hip_bf16.h>

#define NN 8192
#define DD 64
#define NITER 100

typedef unsigned short u16;
typedef unsigned int u32;
typedef float nfloat4 __attribute__((ext_vector_type(4)));  // native vec for NT store

static constexpr float INV_EPS = 10.0f;          // 1/epsilon
static constexpr float MARG    = 1.0f / 8192.0f; // a_i = b_j = u0_i = 1/n

// Unpack 8 bf16 (packed in uint4) -> 8 f32 (exact: bf16 is truncated f32)
__device__ __forceinline__ void unpack8(const uint4 q, float f[8]) {
  f[0] = __uint_as_float(q.x << 16); f[1] = __uint_as_float(q.x & 0xffff0000u);
  f[2] = __uint_as_float(q.y << 16); f[3] = __uint_as_float(q.y & 0xffff0000u);
  f[4] = __uint_as_float(q.z << 16); f[5] = __uint_as_float(q.z & 0xffff0000u);
  f[6] = __uint_as_float(q.w << 16); f[7] = __uint_as_float(q.w & 0xffff0000u);
}

// Pack two f32 -> u32 of 2 bf16 (RNE), low half = first element
__device__ __forceinline__ u32 pkbf2(float a, float b) {
  __hip_bfloat16 ha = __float2bfloat16(a), hb = __float2bfloat16(b);
  return (u32)*reinterpret_cast<u16*>(&ha) | ((u32)*reinterpret_cast<u16*>(&hb) << 16);
}

// ---------------------------------------------------------------------------
// Kernel 1: row norms of x and y. 16384 threads, one row each.
__global__ __launch_bounds__(256) void norms_k(const float* __restrict__ x,
                                               const float* __restrict__ y,
                                               float* __restrict__ xx,
                                               float* __restrict__ yy) {
  int idx = blockIdx.x * 256 + threadIdx.x;       // 0..16383
  const float* src = (idx < NN) ? (x + (size_t)idx * DD)
                                : (y + (size_t)(idx - NN) * DD);
  const float4* p = (const float4*)src;
  float s = 0.f;
#pragma unroll
  for (int i = 0; i < 16; i++) {
    float4 v = p[i];
    s += v.x * v.x + v.y * v.y + v.z * v.z + v.w * v.w;
  }
  if (idx < NN) xx[idx] = s; else yy[idx - NN] = s;
}

// ---------------------------------------------------------------------------
// Kernel 2: build K (bf16), LDS-tiled f32 GEMM. 64x128 tile, micro 4x(4+4).
// R8 known-good: 48 KB LDS -> 3 blocks/CU (occupancy 32%), VALUBusy 76%,
// 158.7 µs measured. R9's 128x128/8x8 variant regressed (64 KB -> 2 blk/CU).
__global__ __launch_bounds__(256) void build_k(const float* __restrict__ x,
                                               const float* __restrict__ y,
                                               const float* __restrict__ xx,
                                               const float* __restrict__ yy,
                                               u16* __restrict__ K) {
  __shared__ float xs[64][64];    // [k][row]  16 KB
  __shared__ float ys[64][128];   // [k][col]  32 KB

  int t  = threadIdx.x;
  int ib = blockIdx.x & 127;      // row block 0..127
  int jb = blockIdx.x >> 7;       // col block 0..63
  int i0 = ib * 64;
  int j0 = jb * 128;

  // stage x: thread t -> row t&63, k-chunk (t>>6)*16. LDS writes 2-way (free).
  {
    int row = t & 63, kc = (t >> 6) * 16;
    const float4* src = (const float4*)(x + (size_t)(i0 + row) * DD + kc);
#pragma unroll
    for (int c = 0; c < 4; c++) {
      float4 v = src[c];
      xs[kc + c * 4 + 0][row] = v.x;
      xs[kc + c * 4 + 1][row] = v.y;
      xs[kc + c * 4 + 2][row] = v.z;
      xs[kc + c * 4 + 3][row] = v.w;
    }
  }
  // stage y: coalesced global float4 reads; transposed write 2-way (free).
  {
    int col = t >> 1, kc = (t & 1) * 32;
    const float4* src = (const float4*)(y + (size_t)(j0 + col) * DD + kc);
#pragma unroll
    for (int c = 0; c < 8; c++) {
      float4 v = src[c];
      ys[kc + c * 4 + 0][col] = v.x;
      ys[kc + c * 4 + 1][col] = v.y;
      ys[kc + c * 4 + 2][col] = v.z;
      ys[kc + c * 4 + 3][col] = v.w;
    }
  }
  __syncthreads();

  int tr = (t >> 4) * 4;          // row offset within tile
  int tc = (t & 15) * 4;          // col group 1; group 2 at tc+64

  float acc[4][8];
#pragma unroll
  for (int r = 0; r < 4; r++)
#pragma unroll
    for (int c = 0; c < 8; c++) acc[r][c] = 0.f;

#pragma unroll 4
  for (int k = 0; k < DD; k++) {
    float4 xa = *(const float4*)&xs[k][tr];
    float4 y0 = *(const float4*)&ys[k][tc];        // banks 2-way: free
    float4 y1 = *(const float4*)&ys[k][tc + 64];   // banks 2-way: free
    float xv[4] = {xa.x, xa.y, xa.z, xa.w};
    float yv[8] = {y0.x, y0.y, y0.z, y0.w, y1.x, y1.y, y1.z, y1.w};
#pragma unroll
    for (int r = 0; r < 4; r++)
#pragma unroll
      for (int c = 0; c < 8; c++) acc[r][c] += xv[r] * yv[c];
  }

  float xn[4], yn[8];
#pragma unroll
  for (int r = 0; r < 4; r++) xn[r] = xx[i0 + tr + r];
#pragma unroll
  for (int c = 0; c < 4; c++) {
    yn[c]     = yy[j0 + tc + c];
    yn[c + 4] = yy[j0 + 64 + tc + c];
  }

#pragma unroll
  for (int r = 0; r < 4; r++) {
    u32 o[4];
#pragma unroll
    for (int c = 0; c < 8; c += 2) {
      float sqa = fmaxf(xn[r] + yn[c]     - 2.f * acc[r][c],     1e-12f);
      float sqb = fmaxf(xn[r] + yn[c + 1] - 2.f * acc[r][c + 1], 1e-12f);
      float ka = __expf(-sqrtf(sqa) * INV_EPS);
      float kb = __expf(-sqrtf(sqb) * INV_EPS);
      o[c >> 1] = pkbf2(ka, kb);
    }
    u16* base = K + (size_t)(i0 + tr + r) * NN + j0;
    *(uint2*)(base + tc)      = make_uint2(o[0], o[1]);
    *(uint2*)(base + 64 + tc) = make_uint2(o[2], o[3]);
  }
}

// ---------------------------------------------------------------------------
// Kernel 3: initial column partials (u0 = 1/n), P bf16.
__global__ __launch_bounds__(256) void col0_k(const u16* __restrict__ K,
                                              u16* __restrict__ P) {
  int t = threadIdx.x;
  int b = blockIdx.x;
  int i0 = b * 16;
  float acc[4][8];
#pragma unroll
  for (int c = 0; c < 4; c++)
#pragma unroll
    for (int e = 0; e < 8; e++) acc[c][e] = 0.f;

  for (int r = 0; r < 16; r++) {
#pragma unroll
    for (int c = 0; c < 4; c++) {
      uint4 q = *(const uint4*)(K + (size_t)(i0 + r) * NN + c * 2048 + t * 8);
      float f[8];
      unpack8(q, f);
#pragma unroll
      for (int e = 0; e < 8; e++) acc[c][e] += f[e];
    }
  }
#pragma unroll
  for (int c = 0; c < 4; c++) {
    uint4 w;
    w.x = pkbf2(acc[c][0] * MARG, acc[c][1] * MARG);
    w.y = pkbf2(acc[c][2] * MARG, acc[c][3] * MARG);
    w.z = pkbf2(acc[c][4] * MARG, acc[c][5] * MARG);
    w.w = pkbf2(acc[c][6] * MARG, acc[c][7] * MARG);
    *(uint4*)(P + (size_t)b * NN + c * 2048 + t * 8) = w;
  }
}

// ---------------------------------------------------------------------------
// Kernel 4: reduce bf16 partials -> v[j] = b_j / sum_k P[k][j].
// 256 blocks x 32 cols (measured-good shape for this latency-bound reduce).
__global__ __launch_bounds__(256) void red_k(const u16* __restrict__ P,
                                             float* __restrict__ v) {
  int t = threadIdx.x;
  int j0 = blockIdx.x * 32;
  int jjp = t & 15;               // col-pair 0..15
  int kk  = t >> 4;               // 0..15, 32 partial rows each
  float s0 = 0.f, s1 = 0.f;
#pragma unroll 8
  for (int k = kk * 32; k < kk * 32 + 32; k++) {
    u32 w = *(const u32*)(P + (size_t)k * NN + j0 + jjp * 2);
    s0 += __uint_as_float(w << 16);
    s1 += __uint_as_float(w & 0xffff0000u);
  }
  __shared__ float red[256][2];
  red[t][0] = s0;
  red[t][1] = s1;
  __syncthreads();
  if (t < 16) {
    float t0 = 0.f, t1 = 0.f;
#pragma unroll
    for (int k = 0; k < 16; k++) {
      t0 += red[k * 16 + t][0];
      t1 += red[k * 16 + t][1];
    }
    v[j0 + t * 2]     = MARG / t0;
    v[j0 + t * 2 + 1] = MARG / t1;
  }
}

// ---------------------------------------------------------------------------
// Kernel 5 (hot loop): fused row-dot + column-partial. Known-good structure:
// 16 rows per block, 8 groups of 2; one barrier per group; 108 VGPR, no
// spill. At the fabric-BW roofline (~5.9 of 6.3-6.6 TB/s) — do not touch.
__global__ __launch_bounds__(256) void fused_k(const u16* __restrict__ K,
                                               const float* __restrict__ vin,
                                               float* __restrict__ uout,
                                               u16* __restrict__ P) {
  int t = threadIdx.x;
  int b = blockIdx.x;
  int i0 = b * 16;
  int wave = t >> 6;

  // v values for this thread's 32 columns
  float vv[4][8];
#pragma unroll
  for (int c = 0; c < 4; c++) {
    const float* vp = vin + c * 2048 + t * 8;
    float4 a = *(const float4*)vp;
    float4 bq = *(const float4*)(vp + 4);
    vv[c][0] = a.x;  vv[c][1] = a.y;  vv[c][2] = a.z;  vv[c][3] = a.w;
    vv[c][4] = bq.x; vv[c][5] = bq.y; vv[c][6] = bq.z; vv[c][7] = bq.w;
  }

  float acc[4][8];
#pragma unroll
  for (int c = 0; c < 4; c++)
#pragma unroll
    for (int e = 0; e < 8; e++) acc[c][e] = 0.f;

  __shared__ float wsum[2][4][2];   // [buf][wave][row]

  for (int rg = 0; rg < 8; rg++) {
    int i = i0 + rg * 2;
    uint4 q0[4], q1[4];
#pragma unroll
    for (int c = 0; c < 4; c++) {
      q0[c] = *(const uint4*)(K + (size_t)i * NN + c * 2048 + t * 8);
      q1[c] = *(const uint4*)(K + (size_t)(i + 1) * NN + c * 2048 + t * 8);
    }
    float s0 = 0.f, s1 = 0.f;
#pragma unroll
    for (int c = 0; c < 4; c++) {
      float f[8];
      unpack8(q0[c], f);
#pragma unroll
      for (int e = 0; e < 8; e++) s0 += f[e] * vv[c][e];
      unpack8(q1[c], f);
#pragma unroll
      for (int e = 0; e < 8; e++) s1 += f[e] * vv[c][e];
    }
    // wave-level reduce (64 lanes)
#pragma unroll
    for (int o = 32; o > 0; o >>= 1) {
      s0 += __shfl_xor(s0, o);
      s1 += __shfl_xor(s1, o);
    }
    if ((t & 63) == 0) {
      wsum[rg & 1][wave][0] = s0;
      wsum[rg & 1][wave][1] = s1;
    }
    __syncthreads();
    float u0 = MARG / (wsum[rg & 1][0][0] + wsum[rg & 1][1][0]
                     + wsum[rg & 1][2][0] + wsum[rg & 1][3][0]);
    float u1 = MARG / (wsum[rg & 1][0][1] + wsum[rg & 1][1][1]
                     + wsum[rg & 1][2][1] + wsum[rg & 1][3][1]);
    if (t < 2) uout[i + t] = (t == 0) ? u0 : u1;

    // accumulate column partials (re-unpack from regs)
#pragma unroll
    for (int c = 0; c < 4; c++) {
      float f[8];
      unpack8(q0[c], f);
#pragma unroll
      for (int e = 0; e < 8; e++) acc[c][e] += f[e] * u0;
      unpack8(q1[c], f);
#pragma unroll
      for (int e = 0; e < 8; e++) acc[c][e] += f[e] * u1;
    }
  }

#pragma unroll
  for (int c = 0; c < 4; c++) {
    uint4 w;
    w.x = pkbf2(acc[c][0], acc[c][1]);
    w.y = pkbf2(acc[c][2], acc[c][3]);
    w.z = pkbf2(acc[c][4], acc[c][5]);
    w.w = pkbf2(acc[c][6], acc[c][7]);
    *(uint4*)(P + (size_t)b * NN + c * 2048 + t * 8) = w;
  }
}

// ---------------------------------------------------------------------------
// Kernel 6: pi[i][j] = u_i * K[i][j] * v_j. 4096 blocks x 2 rows; NT stores.
__global__ __launch_bounds__(256) void pi_k(const u16* __restrict__ K,
                                            const float* __restrict__ u,
                                            const float* __restrict__ v,
                                            float* __restrict__ out) {
  int t = threadIdx.x;
  int b = blockIdx.x;
  int i0 = b * 2;

  float vv[4][8];
#pragma unroll
  for (int c = 0; c < 4; c++) {
    const float* vp = v + c * 2048 + t * 8;
    float4 a = *(const float4*)vp;
    float4 bq = *(const float4*)(vp + 4);
    vv[c][0] = a.x;  vv[c][1] = a.y;  vv[c][2] = a.z;  vv[c][3] = a.w;
    vv[c][4] = bq.x; vv[c][5] = bq.y; vv[c][6] = bq.z; vv[c][7] = bq.w;
  }

#pragma unroll
  for (int r = 0; r < 2; r++) {
    int i = i0 + r;
    float uv = u[i];
#pragma unroll
    for (int c = 0; c < 4; c++) {
      uint4 q = *(const uint4*)(K + (size_t)i * NN + c * 2048 + t * 8);
      float f[8];
      unpack8(q, f);
      nfloat4 lo = {uv * f[0] * vv[c][0], uv * f[1] * vv[c][1],
                    uv * f[2] * vv[c][2], uv * f[3] * vv[c][3]};
      nfloat4 hi = {uv * f[4] * vv[c][4], uv * f[5] * vv[c][5],
                    uv * f[6] * vv[c][6], uv * f[7] * vv[c][7]};
      float* dst = out + (size_t)i * NN + c * 2048 + t * 8;
      __builtin_nontemporal_store(lo, (nfloat4*)dst);
      __builtin_nontemporal_store(hi, (nfloat4*)(dst + 4));
    }
  }
}

// ---------------------------------------------------------------------------
extern "C" void kernel_launch(void* const* d_in, const int* in_sizes, int n_in,
                              void* d_out, int out_size, void* d_ws, size_t ws_size,
                              hipStream_t stream) {
  const float* x = (const float*)d_in[0];
  const float* y = (const float*)d_in[1];
  float* out = (float*)d_out;

  char* ws = (char*)d_ws;
  u16*  K  = (u16*)ws;                                     // 128 MiB
  u16*  P  = (u16*)(ws + (size_t)NN * NN * 2);             // 8 MiB (512 x 8192 bf16)
  float* xx = (float*)(ws + (size_t)NN * NN * 2 + (size_t)512 * NN * 2);
  float* yy = xx + NN;
  float* u  = yy + NN;
  float* v  = u + NN;

  norms_k<<<(2 * NN) / 256, 256, 0, stream>>>(x, y, xx, yy);
  build_k<<<128 * 64, 256, 0, stream>>>(x, y, xx, yy, K);
  col0_k<<<NN / 16, 256, 0, stream>>>(K, P);               // P = partials of K^T u0

  for (int it = 0; it < NITER; it++) {
    red_k<<<NN / 32, 256, 0, stream>>>(P, v);              // v = b / (K^T u)
    fused_k<<<NN / 16, 256, 0, stream>>>(K, v, u, P);      // u = a/(Kv); P = partials K^T u
  }
  red_k<<<NN / 32, 256, 0, stream>>>(P, v);                // final v
  pi_k<<<NN / 2, 256, 0, stream>>>(K, u, v, out);          // pi = u * K * v
}